// Round 12
// baseline (512.935 us; speedup 1.0000x reference)
//
#include <hip/hip_runtime.h>
#include <hip/hip_fp16.h>
#include <math.h>

#define NB_NODES 100000
#define NB_EDGES 1600000
#define NB_GRAPHS 1000
#define CAP 232
#define NBLK1 400      // coarse pass blocks
#define CHUNK 4000     // edges per coarse block (NBLK1*CHUNK == NB_EDGES)
#define NBUCK 391      // ceil(NB_NODES/256) coarse buckets (dst >> 8)
#define BCAP 4608      // max edges per bucket (mean 4096, sigma 64, +8 sigma)
#define SLICE_STRIDE (NB_NODES * 8)   // halfs per feature-slice region
constexpr float GN_EPS = 1e-5f;

// slice-major layout: element (node n, feature f) lives at
//   (f>>3)*SLICE_STRIDE + n*8 + (f&7)   [halfs]
// so slice s holds a contiguous [N x 16B] region (1.6 MB -> fits one XCD L2).
__device__ __forceinline__ int smoff(int n, int f) {
    return (f >> 3) * SLICE_STRIDE + n * 8 + (f & 7);
}

// ---- K1: per-block LDS histogram over coarse buckets + gstart (blocks 0-3) ----
__global__ __launch_bounds__(256) void k1_hist(const int* __restrict__ dst,
    int* __restrict__ hist, const int* __restrict__ batch, int* __restrict__ gstart) {
    __shared__ int h[NBUCK];
    int tid = threadIdx.x;
    for (int i = tid; i < NBUCK; i += 256) h[i] = 0;
    if (blockIdx.x < 4) {
        int g = blockIdx.x * 256 + tid;
        if (g <= NB_GRAPHS) {
            int lo = 0, hi = NB_NODES;
            while (lo < hi) {
                int mid = (lo + hi) >> 1;
                if (batch[mid] < g) lo = mid + 1; else hi = mid;
            }
            gstart[g] = lo;
        }
    }
    __syncthreads();
    int base = blockIdx.x * CHUNK;
    for (int i = tid; i < CHUNK; i += 256) atomicAdd(&h[dst[base + i] >> 8], 1);
    __syncthreads();
    for (int i = tid; i < NBUCK; i += 256) hist[blockIdx.x * NBUCK + i] = h[i];
}

// ---- K2a: per bucket, exclusive scan across the 400 blocks; emit totals ----
__global__ __launch_bounds__(512) void k2a_scan(int* __restrict__ hist,
                                                int* __restrict__ total) {
    __shared__ int s[512];
    int b = blockIdx.x;  // bucket
    int tid = threadIdx.x;
    int v = (tid < NBLK1) ? hist[tid * NBUCK + b] : 0;
    s[tid] = v;
    __syncthreads();
    for (int o = 1; o < 512; o <<= 1) {
        int t = (tid >= o) ? s[tid - o] : 0;
        __syncthreads();
        s[tid] += t;
        __syncthreads();
    }
    if (tid < NBLK1) hist[tid * NBUCK + b] = s[tid] - v;  // exclusive prefix in place
    if (tid == 511) total[b] = s[511];
}

// ---- K2b: exclusive scan of bucket totals -> base[NBUCK+1] ----
__global__ __launch_bounds__(512) void k2b_scan(const int* __restrict__ total,
                                                int* __restrict__ base) {
    __shared__ int s[512];
    int tid = threadIdx.x;
    int v = (tid < NBUCK) ? total[tid] : 0;
    s[tid] = v;
    __syncthreads();
    for (int o = 1; o < 512; o <<= 1) {
        int t = (tid >= o) ? s[tid - o] : 0;
        __syncthreads();
        s[tid] += t;
        __syncthreads();
    }
    if (tid < NBUCK) base[tid] = s[tid] - v;
    if (tid == NBUCK) base[NBUCK] = NB_EDGES;
}

// ---- K3: scatter packed edges into bucket-contiguous runs (LDS cursors) ----
__global__ __launch_bounds__(256) void k3_scatter(const int* __restrict__ ei,
    const int* __restrict__ hist, const int* __restrict__ base,
    unsigned int* __restrict__ ebuf) {
    __shared__ int cur[NBUCK];
    int tid = threadIdx.x;
    for (int i = tid; i < NBUCK; i += 256)
        cur[i] = base[i] + hist[blockIdx.x * NBUCK + i];
    __syncthreads();
    int eb = blockIdx.x * CHUNK;
    for (int i = tid; i < CHUNK; i += 256) {
        int e = eb + i;
        int sidx = ei[e];
        int d = ei[NB_EDGES + e];
        int pos = atomicAdd(&cur[d >> 8], 1);
        ebuf[pos] = (unsigned int)sidx | ((unsigned int)(d & 255) << 24);
    }
}

// ---- K4: per-bucket fine CSR in LDS; coalesced csr_src/rowptr/dinv writes ----
__global__ __launch_bounds__(256) void k4_fine(const unsigned int* __restrict__ ebuf,
    const int* __restrict__ base, int* __restrict__ csr_src, int* __restrict__ rowptr,
    float* __restrict__ dinv) {
    __shared__ unsigned int epk[BCAP];
    __shared__ int outb[BCAP];
    __shared__ int cnt[256];
    __shared__ int sbuf[256];
    __shared__ int cur2[256];
    int b = blockIdx.x;
    int tid = threadIdx.x;
    int eb = base[b], ee = base[b + 1];
    int m = ee - eb;
    if (m > BCAP) m = BCAP;  // memory-safety clamp (never expected)
    for (int i = tid; i < m; i += 256) epk[i] = ebuf[eb + i];
    cnt[tid] = 0;
    __syncthreads();
    for (int i = tid; i < m; i += 256) atomicAdd(&cnt[epk[i] >> 24], 1);
    __syncthreads();
    int c = cnt[tid];
    sbuf[tid] = c;
    __syncthreads();
    for (int o = 1; o < 256; o <<= 1) {
        int t = (tid >= o) ? sbuf[tid - o] : 0;
        __syncthreads();
        sbuf[tid] += t;
        __syncthreads();
    }
    int off = sbuf[tid] - c;  // exclusive scan
    cur2[tid] = off;
    __syncthreads();
    for (int i = tid; i < m; i += 256) {
        unsigned int p = epk[i];
        int r = atomicAdd(&cur2[p >> 24], 1);
        outb[r] = (int)(p & 0x00FFFFFFu);
    }
    __syncthreads();
    for (int i = tid; i < m; i += 256) csr_src[eb + i] = outb[i];
    int node = b * 256 + tid;
    if (node < NB_NODES) {
        rowptr[node] = eb + off;
        dinv[node] = rsqrtf((float)(c + 1));
    }
    if (b == 0 && tid == 0) rowptr[NB_NODES] = NB_EDGES;
}

// ---------------- fp16 helpers ----------------
union HU {
    uint4 u;
    __half2 h[4];
};

// --- aggregate (slice-partitioned): slice = blockIdx&7 -> XCD via round-robin.
// Each XCD gathers only from its 1.6 MB slice region (L2-resident).
// One node per thread; fp32 accumulate; depth-2 gather pipeline.
// hs rows prescaled by dinv[src]. out = relu(dinv[dst]*(self+sum) + bias), fp16.
__global__ __launch_bounds__(256) void aggregate_s_k(const __half* __restrict__ hs,
    const int* __restrict__ rowptr, const int* __restrict__ csr_src,
    const float* __restrict__ dinv, const float* __restrict__ bias,
    __half* __restrict__ out) {
    int s = blockIdx.x & 7;                      // feature slice / XCD
    int n = (blockIdx.x >> 3) * 256 + threadIdx.x;
    if (n >= NB_NODES) return;
    const uint4* hsv = (const uint4*)hs + (size_t)s * NB_NODES;
    int rs = rowptr[n], re = rowptr[n + 1];
    // self term (coalesced: consecutive threads -> consecutive uint4)
    HU x; x.u = hsv[n];
    float2 f0 = __half22float2(x.h[0]), f1 = __half22float2(x.h[1]);
    float2 f2 = __half22float2(x.h[2]), f3 = __half22float2(x.h[3]);
    float a0 = f0.x, a1 = f0.y, a2 = f1.x, a3 = f1.y;
    float a4 = f2.x, a5 = f2.y, a6 = f3.x, a7 = f3.y;
    if (re > rs) {
        uint4 g0 = hsv[csr_src[rs]];
        for (int j = rs + 1; j < re; j++) {
            uint4 g1 = hsv[csr_src[j]];          // next gather in flight
            HU y; y.u = g0;
            float2 h0 = __half22float2(y.h[0]), h1 = __half22float2(y.h[1]);
            float2 h2 = __half22float2(y.h[2]), h3 = __half22float2(y.h[3]);
            a0 += h0.x; a1 += h0.y; a2 += h1.x; a3 += h1.y;
            a4 += h2.x; a5 += h2.y; a6 += h3.x; a7 += h3.y;
            g0 = g1;
        }
        HU y; y.u = g0;
        float2 h0 = __half22float2(y.h[0]), h1 = __half22float2(y.h[1]);
        float2 h2 = __half22float2(y.h[2]), h3 = __half22float2(y.h[3]);
        a0 += h0.x; a1 += h0.y; a2 += h1.x; a3 += h1.y;
        a4 += h2.x; a5 += h2.y; a6 += h3.x; a7 += h3.y;
    }
    float dn = dinv[n];
    // bias of this slice: lane-uniform -> scalar loads
    float b0 = bias[s * 8 + 0], b1 = bias[s * 8 + 1];
    float b2 = bias[s * 8 + 2], b3 = bias[s * 8 + 3];
    float b4 = bias[s * 8 + 4], b5 = bias[s * 8 + 5];
    float b6 = bias[s * 8 + 6], b7 = bias[s * 8 + 7];
    float r0 = fmaf(a0, dn, b0), r1 = fmaf(a1, dn, b1);
    float r2 = fmaf(a2, dn, b2), r3 = fmaf(a3, dn, b3);
    float r4 = fmaf(a4, dn, b4), r5 = fmaf(a5, dn, b5);
    float r6 = fmaf(a6, dn, b6), r7 = fmaf(a7, dn, b7);
    r0 = r0 > 0.f ? r0 : 0.f; r1 = r1 > 0.f ? r1 : 0.f;
    r2 = r2 > 0.f ? r2 : 0.f; r3 = r3 > 0.f ? r3 : 0.f;
    r4 = r4 > 0.f ? r4 : 0.f; r5 = r5 > 0.f ? r5 : 0.f;
    r6 = r6 > 0.f ? r6 : 0.f; r7 = r7 > 0.f ? r7 : 0.f;
    HU o;
    o.h[0] = __floats2half2_rn(r0, r1);
    o.h[1] = __floats2half2_rn(r2, r3);
    o.h[2] = __floats2half2_rn(r4, r5);
    o.h[3] = __floats2half2_rn(r6, r7);
    ((uint4*)out)[(size_t)s * NB_NODES + n] = o.u;
}

// ------- normlin: GraphNorm(64) single-pass stats + linear 64x64 + dinv -----------
// A and out are slice-major.
__global__ __launch_bounds__(512) void normlin_k(const __half* __restrict__ A,
    const int* __restrict__ gstart, const float* __restrict__ gw,
    const float* __restrict__ gb, const float* __restrict__ ga,
    const float* __restrict__ W, const float* __restrict__ dinv,
    __half* __restrict__ out) {
    __shared__ float sW[64 * 64];
    __shared__ float red[512], red2[512];
    __shared__ float sam[64], ssc[64];
    __shared__ float srow[8 * 64];
    int tid = threadIdx.x, lane = tid & 63, wid = tid >> 6;
    int g = blockIdx.x;
    int s = gstart[g], e = gstart[g + 1], cnt = e - s;
    float cntf = (float)(cnt > 1 ? cnt : 1);
    for (int i = tid; i < 64 * 64; i += 512) sW[i] = W[i];
    float sum = 0.f, sq = 0.f;
    for (int i = s + wid; i < e; i += 8) {
        float v = __half2float(A[smoff(i, lane)]);
        sum += v;
        sq = fmaf(v, v, sq);
    }
    red[tid] = sum; red2[tid] = sq;
    __syncthreads();
    for (int st = 4; st > 0; st >>= 1) {
        if (wid < st) { red[tid] += red[tid + st * 64]; red2[tid] += red2[tid + st * 64]; }
        __syncthreads();
    }
    if (tid < 64) {
        float m = red[tid] / cntf, q = red2[tid] / cntf;
        float am = ga[tid] * m;
        float var = q - 2.f * am * m + am * am;
        sam[tid] = am;
        ssc[tid] = gw[tid] * rsqrtf(var + GN_EPS);
    }
    __syncthreads();
    float am = sam[lane], sc = ssc[lane], bb = gb[lane];
    for (int i = s + wid; i < e; i += 8) {
        float nv = (__half2float(A[smoff(i, lane)]) - am) * sc + bb;
        srow[wid * 64 + lane] = nv;
        float acc = 0.f;
#pragma unroll
        for (int k = 0; k < 64; k++) acc = fmaf(srow[wid * 64 + k], sW[k * 64 + lane], acc);
        out[smoff(i, lane)] = __float2half(acc * dinv[i]);
    }
}

// ---------------- layer0: GraphNorm(16) + linear 16->64 (block per graph) ---------
__device__ __forceinline__ void l0_body(float* rows, int cnt, int s,
    const float* __restrict__ x, const float* __restrict__ gw,
    const float* __restrict__ gb, const float* __restrict__ ga,
    const float* sW, const float* __restrict__ dinv, __half* __restrict__ hs_out,
    float* red, float* red2, float* sstat, float* sscale, int tid) {
    int f = tid & 15, r = tid >> 4;
    int lane = tid & 63, wid = tid >> 6;
    float cntf = (float)(cnt > 1 ? cnt : 1);
    float sum = 0.f, sq = 0.f;
    for (int i = r; i < cnt; i += 32) {
        float v = x[(size_t)(s + i) * 16 + f];
        rows[i * 16 + f] = v;
        sum += v;
        sq = fmaf(v, v, sq);
    }
    red[tid] = sum; red2[tid] = sq;
    __syncthreads();
    for (int st = 16; st > 0; st >>= 1) {
        if (r < st) { red[tid] += red[tid + st * 16]; red2[tid] += red2[tid + st * 16]; }
        __syncthreads();
    }
    if (tid < 16) {
        float m = red[tid] / cntf, q = red2[tid] / cntf;
        float am = ga[tid] * m;
        sstat[tid] = am;
        sscale[tid] = gw[tid] * rsqrtf(q - 2.f * am * m + am * am + GN_EPS);
    }
    __syncthreads();
    float am = sstat[f], sc = sscale[f], bb = gb[f];
    for (int i = r; i < cnt; i += 32) rows[i * 16 + f] = (rows[i * 16 + f] - am) * sc + bb;
    __syncthreads();
    for (int i = wid; i < cnt; i += 8) {
        float acc = 0.f;
#pragma unroll
        for (int k = 0; k < 16; k++) acc = fmaf(rows[i * 16 + k], sW[k * 64 + lane], acc);
        hs_out[smoff(s + i, lane)] = __float2half(acc * dinv[s + i]);
    }
}

__global__ __launch_bounds__(512) void layer0_k(const float* __restrict__ x,
    const int* __restrict__ gstart, const float* __restrict__ gw,
    const float* __restrict__ gb, const float* __restrict__ ga,
    const float* __restrict__ W, const float* __restrict__ dinv,
    __half* __restrict__ hs_out, float* __restrict__ spill16) {
    __shared__ float sRows[CAP * 16];
    __shared__ float sW[16 * 64];
    __shared__ float red[512], red2[512];
    __shared__ float sstat[16], sscale[16];
    int tid = threadIdx.x;
    int g = blockIdx.x;
    int s = gstart[g], e = gstart[g + 1], cnt = e - s;
    for (int i = tid; i < 16 * 64; i += 512) sW[i] = W[i];
    __syncthreads();
    if (cnt <= CAP)
        l0_body(sRows, cnt, s, x, gw, gb, ga, sW, dinv, hs_out, red, red2, sstat, sscale, tid);
    else
        l0_body(spill16 + (size_t)s * 16, cnt, s, x, gw, gb, ga, sW, dinv, hs_out, red, red2, sstat, sscale, tid);
}

// ---------------- Pool + MLP head + softmax: block per graph ----------------
__global__ void pool_head_k(const __half* __restrict__ x, const int* __restrict__ gstart,
                            const float* __restrict__ Wd, const float* __restrict__ bd,
                            const float* __restrict__ Wo, const float* __restrict__ bo,
                            float* __restrict__ out) {
    __shared__ float red[256];
    __shared__ float sp[64];
    __shared__ float sh[64];
    __shared__ float sl[2];
    int g = blockIdx.x;
    int s = gstart[g], e = gstart[g + 1];
    int cnt = e - s;
    float cntf = (float)(cnt > 1 ? cnt : 1);
    int tid = threadIdx.x;
    int f = tid & 63, r = tid >> 6;
    float sum = 0.f;
    for (int i = s + r; i < e; i += 4) sum += __half2float(x[smoff(i, f)]);
    red[tid] = sum;
    __syncthreads();
    for (int st = 2; st > 0; st >>= 1) {
        if (r < st) red[tid] += red[tid + st * 64];
        __syncthreads();
    }
    if (tid < 64) sp[tid] = red[tid] / cntf;
    __syncthreads();
    if (tid < 64) {
        float acc = bd[tid];
        for (int k = 0; k < 64; k++) acc = fmaf(sp[k], Wd[k * 64 + tid], acc);
        sh[tid] = acc > 0.f ? acc : 0.f;
    }
    __syncthreads();
    if (tid < 2) {
        float l = bo[tid];
        for (int k = 0; k < 64; k++) l = fmaf(sh[k], Wo[k * 2 + tid], l);
        sl[tid] = l;
    }
    __syncthreads();
    if (tid < 2) {
        float m = fmaxf(sl[0], sl[1]);
        float e0 = expf(sl[0] - m), e1 = expf(sl[1] - m);
        out[g * 2 + tid] = (tid == 0 ? e0 : e1) / (e0 + e1);
    }
}

extern "C" void kernel_launch(void* const* d_in, const int* in_sizes, int n_in,
                              void* d_out, int out_size, void* d_ws, size_t ws_size,
                              hipStream_t stream) {
    const float* x    = (const float*)d_in[0];
    const int* ei     = (const int*)d_in[1];
    const int* batch  = (const int*)d_in[2];
    const float* gn0w = (const float*)d_in[3];
    const float* gn0b = (const float*)d_in[4];
    const float* gn0a = (const float*)d_in[5];
    const float* W1   = (const float*)d_in[6];
    const float* b1   = (const float*)d_in[7];
    const float* gn1w = (const float*)d_in[8];
    const float* gn1b = (const float*)d_in[9];
    const float* gn1a = (const float*)d_in[10];
    const float* W2   = (const float*)d_in[11];
    const float* b2   = (const float*)d_in[12];
    const float* gn2w = (const float*)d_in[13];
    const float* gn2b = (const float*)d_in[14];
    const float* gn2a = (const float*)d_in[15];
    const float* W3   = (const float*)d_in[16];
    const float* b3   = (const float*)d_in[17];
    const float* Wd   = (const float*)d_in[18];
    const float* bd   = (const float*)d_in[19];
    const float* Wo   = (const float*)d_in[20];
    const float* bo   = (const float*)d_in[21];

    char* p = (char*)d_ws;
    auto alloc = [&](size_t bytes) -> void* {
        void* r = (void*)p;
        p += (bytes + 255) & ~(size_t)255;
        return r;
    };
    __half* A        = (__half*)alloc((size_t)NB_NODES * 64 * 2);
    __half* B        = (__half*)alloc((size_t)NB_NODES * 64 * 2);
    int* rowptr      = (int*)alloc((size_t)(NB_NODES + 1) * 4);
    unsigned* ebuf   = (unsigned*)alloc((size_t)NB_EDGES * 4);
    int* csr_src     = (int*)alloc((size_t)NB_EDGES * 4);
    int* hist        = (int*)alloc((size_t)NBLK1 * NBUCK * 4);
    int* total       = (int*)alloc((size_t)NBUCK * 4);
    int* basearr     = (int*)alloc((size_t)(NBUCK + 1) * 4);
    float* dinv      = (float*)alloc((size_t)NB_NODES * 4);
    int* gstart      = (int*)alloc((size_t)(NB_GRAPHS + 1) * 4);
    float* spill16   = (float*)alloc((size_t)NB_NODES * 16 * 4);

    k1_hist<<<NBLK1, 256, 0, stream>>>(ei + NB_EDGES, hist, batch, gstart);
    k2a_scan<<<NBUCK, 512, 0, stream>>>(hist, total);
    k2b_scan<<<1, 512, 0, stream>>>(total, basearr);
    k3_scatter<<<NBLK1, 256, 0, stream>>>(ei, hist, basearr, ebuf);
    k4_fine<<<NBUCK, 256, 0, stream>>>(ebuf, basearr, csr_src, rowptr, dinv);

    layer0_k<<<NB_GRAPHS, 512, 0, stream>>>(x, gstart, gn0w, gn0b, gn0a, W1, dinv, B, spill16);
    aggregate_s_k<<<3128, 256, 0, stream>>>(B, rowptr, csr_src, dinv, b1, A);
    normlin_k<<<NB_GRAPHS, 512, 0, stream>>>(A, gstart, gn1w, gn1b, gn1a, W2, dinv, B);
    aggregate_s_k<<<3128, 256, 0, stream>>>(B, rowptr, csr_src, dinv, b2, A);
    normlin_k<<<NB_GRAPHS, 512, 0, stream>>>(A, gstart, gn2w, gn2b, gn2a, W3, dinv, B);
    aggregate_s_k<<<3128, 256, 0, stream>>>(B, rowptr, csr_src, dinv, b3, A);
    pool_head_k<<<NB_GRAPHS, 256, 0, stream>>>(A, gstart, Wd, bd, Wo, bo, (float*)d_out);
}

// Round 13
// 320.908 us; speedup vs baseline: 1.5984x; 1.5984x over previous
//
#include <hip/hip_runtime.h>
#include <hip/hip_fp16.h>
#include <math.h>

#define NB_NODES 100000
#define NB_EDGES 1600000
#define NB_GRAPHS 1000
#define CAP 232
#define NBLK1 400      // coarse pass blocks
#define CHUNK 4000     // edges per coarse block (NBLK1*CHUNK == NB_EDGES)
#define NBUCK 391      // ceil(NB_NODES/256) coarse buckets (dst >> 8)
#define BCAP 4608      // max edges per bucket (mean 4096, sigma 64, +8 sigma)
constexpr float GN_EPS = 1e-5f;

// ---- K1: per-block LDS histogram over coarse buckets + gstart (blocks 0-3) ----
__global__ __launch_bounds__(256) void k1_hist(const int* __restrict__ dst,
    int* __restrict__ hist, const int* __restrict__ batch, int* __restrict__ gstart) {
    __shared__ int h[NBUCK];
    int tid = threadIdx.x;
    for (int i = tid; i < NBUCK; i += 256) h[i] = 0;
    if (blockIdx.x < 4) {
        int g = blockIdx.x * 256 + tid;
        if (g <= NB_GRAPHS) {
            int lo = 0, hi = NB_NODES;
            while (lo < hi) {
                int mid = (lo + hi) >> 1;
                if (batch[mid] < g) lo = mid + 1; else hi = mid;
            }
            gstart[g] = lo;
        }
    }
    __syncthreads();
    int base = blockIdx.x * CHUNK;
    for (int i = tid; i < CHUNK; i += 256) atomicAdd(&h[dst[base + i] >> 8], 1);
    __syncthreads();
    for (int i = tid; i < NBUCK; i += 256) hist[blockIdx.x * NBUCK + i] = h[i];
}

// ---- K2: per bucket, exclusive scan across the 400 blocks; emit totals ----
__global__ __launch_bounds__(512) void k2a_scan(int* __restrict__ hist,
                                                int* __restrict__ total) {
    __shared__ int s[512];
    int b = blockIdx.x;  // bucket
    int tid = threadIdx.x;
    int v = (tid < NBLK1) ? hist[tid * NBUCK + b] : 0;
    s[tid] = v;
    __syncthreads();
    for (int o = 1; o < 512; o <<= 1) {
        int t = (tid >= o) ? s[tid - o] : 0;
        __syncthreads();
        s[tid] += t;
        __syncthreads();
    }
    if (tid < NBLK1) hist[tid * NBUCK + b] = s[tid] - v;  // exclusive prefix in place
    if (tid == 511) total[b] = s[511];
}

// ---- K3: scatter into bucket-contiguous runs; base recomputed in-LDS from total ----
__global__ __launch_bounds__(256) void k3_scatter(const int* __restrict__ ei,
    const int* __restrict__ hist, const int* __restrict__ total,
    unsigned int* __restrict__ ebuf) {
    __shared__ int cur[NBUCK];
    __shared__ int sc[256];
    int tid = threadIdx.x;
    // redundant per-block base scan (391 totals, pair-per-thread Hillis-Steele)
    int e0 = 2 * tid, e1 = 2 * tid + 1;
    int v0 = (e0 < NBUCK) ? total[e0] : 0;
    int v1 = (e1 < NBUCK) ? total[e1] : 0;
    int own = v0 + v1;
    sc[tid] = own;
    __syncthreads();
    for (int o = 1; o < 256; o <<= 1) {
        int t = (tid >= o) ? sc[tid - o] : 0;
        __syncthreads();
        sc[tid] += t;
        __syncthreads();
    }
    int pre = sc[tid] - own;
    if (e0 < NBUCK) cur[e0] = pre + hist[blockIdx.x * NBUCK + e0];
    if (e1 < NBUCK) cur[e1] = pre + v0 + hist[blockIdx.x * NBUCK + e1];
    __syncthreads();
    int eb = blockIdx.x * CHUNK;
    for (int i = tid; i < CHUNK; i += 256) {
        int e = eb + i;
        int sidx = ei[e];
        int d = ei[NB_EDGES + e];
        int pos = atomicAdd(&cur[d >> 8], 1);
        ebuf[pos] = (unsigned int)sidx | ((unsigned int)(d & 255) << 24);
    }
}

// ---- K4: per-bucket fine CSR in LDS; base recomputed in-LDS from total ----
__global__ __launch_bounds__(256) void k4_fine(const unsigned int* __restrict__ ebuf,
    const int* __restrict__ total, int* __restrict__ csr_src, int* __restrict__ rowptr,
    float* __restrict__ dinv) {
    __shared__ int arena[2 * BCAP + 768];
    unsigned int* epk = (unsigned int*)arena;
    int* outb  = arena + BCAP;
    int* cnt   = arena + 2 * BCAP;          // 256
    int* sbuf  = arena + 2 * BCAP + 256;    // 256
    int* cur2  = arena + 2 * BCAP + 512;    // 256
    int* bases = arena + 2 * BCAP;          // 392 ints, phase0 only (overlaps cnt/sbuf)
    int b = blockIdx.x;
    int tid = threadIdx.x;
    // phase0: recompute base[b], base[b+1] from total[] (scan arena = cur2)
    int e0 = 2 * tid, e1 = 2 * tid + 1;
    int v0 = (e0 < NBUCK) ? total[e0] : 0;
    int v1 = (e1 < NBUCK) ? total[e1] : 0;
    int own = v0 + v1;
    cur2[tid] = own;
    __syncthreads();
    for (int o = 1; o < 256; o <<= 1) {
        int t = (tid >= o) ? cur2[tid - o] : 0;
        __syncthreads();
        cur2[tid] += t;
        __syncthreads();
    }
    int pre = cur2[tid] - own;
    if (e0 < NBUCK) bases[e0] = pre;
    if (e1 < NBUCK) bases[e1] = pre + v0;
    if (tid == 0) bases[NBUCK] = NB_EDGES;
    __syncthreads();
    int eb = bases[b], ee = bases[b + 1];
    __syncthreads();  // done with bases; cnt/sbuf reusable
    int m = ee - eb;
    if (m > BCAP) m = BCAP;  // memory-safety clamp (never expected)
    for (int i = tid; i < m; i += 256) epk[i] = ebuf[eb + i];
    cnt[tid] = 0;
    __syncthreads();
    for (int i = tid; i < m; i += 256) atomicAdd(&cnt[epk[i] >> 24], 1);
    __syncthreads();
    int c = cnt[tid];
    sbuf[tid] = c;
    __syncthreads();
    for (int o = 1; o < 256; o <<= 1) {
        int t = (tid >= o) ? sbuf[tid - o] : 0;
        __syncthreads();
        sbuf[tid] += t;
        __syncthreads();
    }
    int off = sbuf[tid] - c;  // exclusive scan
    cur2[tid] = off;
    __syncthreads();
    for (int i = tid; i < m; i += 256) {
        unsigned int p = epk[i];
        int r = atomicAdd(&cur2[p >> 24], 1);
        outb[r] = (int)(p & 0x00FFFFFFu);
    }
    __syncthreads();
    for (int i = tid; i < m; i += 256) csr_src[eb + i] = outb[i];
    int node = b * 256 + tid;
    if (node < NB_NODES) {
        rowptr[node] = eb + off;
        dinv[node] = rsqrtf((float)(c + 1));
    }
    if (b == 0 && tid == 0) rowptr[NB_NODES] = NB_EDGES;
}

// ---------------- fp16 helpers ----------------
union HU {
    uint4 u;
    __half2 h[4];
};

__device__ __forceinline__ void pkacc(__half2* a, uint4 v) {
    HU x; x.u = v;
    a[0] = __hadd2(a[0], x.h[0]);
    a[1] = __hadd2(a[1], x.h[1]);
    a[2] = __hadd2(a[2], x.h[2]);
    a[3] = __hadd2(a[3], x.h[3]);
}

__device__ __forceinline__ __half2 shxor_h2(__half2 v, int m) {
    union { __half2 h; int i; } u;
    u.h = v;
    u.i = __shfl_xor(u.i, m, 64);
    return u.h;
}

// --- aggregate: 4 nodes/wave; one coalesced idx load per node covers deg<=64;
// gathers issued in two groups of 8 (nodes 0,1 then 2,3) -> ~18 loads in flight.
// hs rows prescaled by dinv[src]. out = relu(dinv[dst]*(self + sum_src) + bias), fp16
__global__ __launch_bounds__(256) void aggregate_h_k(const __half* __restrict__ hs,
    const int* __restrict__ rowptr, const int* __restrict__ csr_src,
    const float* __restrict__ dinv, const float* __restrict__ bias,
    __half* __restrict__ out) {
    const uint4* hsv = (const uint4*)hs;  // row = 8 uint4 (64 fp16)
    int wv = blockIdx.x * 4 + (threadIdx.x >> 6);
    int lane = threadIdx.x & 63;
    int f8 = lane & 7;   // 16B chunk: features [f8*8, f8*8+8)
    int e8 = lane >> 3;  // edge slot 0..7
    int n0 = __builtin_amdgcn_readfirstlane(wv * 4);
    int r0 = rowptr[n0], r1 = rowptr[n0 + 1], r2 = rowptr[n0 + 2];
    int r3 = rowptr[n0 + 3], r4 = rowptr[n0 + 4];          // scalar loads
    int d0 = r1 - r0, d1 = r2 - r1, d2 = r3 - r2, d3 = r4 - r3;
    const uint4 Z = {0u, 0u, 0u, 0u};
    // one coalesced index load per node: lane i -> edge i (valid for deg<=64)
    int idx0 = (lane < d0) ? csr_src[r0 + lane] : -1;
    int idx1 = (lane < d1) ? csr_src[r1 + lane] : -1;
    int idx2 = (lane < d2) ? csr_src[r2 + lane] : -1;
    int idx3 = (lane < d3) ? csr_src[r3 + lane] : -1;
    // self rows: e8 slot k loads node n0+k's row
    uint4 self = Z;
    if (e8 < 4) self = hsv[(size_t)(n0 + e8) * 8 + f8];
    // group A gathers: nodes 0,1 blocks 0..3 (8 loads in flight)
    uint4 gA[8];
#pragma unroll
    for (int b = 0; b < 4; b++) {
        int u = __shfl(idx0, b * 8 + e8, 64);
        gA[b] = Z;
        if (u >= 0) gA[b] = hsv[(size_t)u * 8 + f8];
        int v = __shfl(idx1, b * 8 + e8, 64);
        gA[4 + b] = Z;
        if (v >= 0) gA[4 + b] = hsv[(size_t)v * 8 + f8];
    }
    __half2 acc0[4], acc1[4], acc2[4], acc3[4];
    __half2 z2{__half(0.f), __half(0.f)};
    acc0[0] = acc0[1] = acc0[2] = acc0[3] = z2;
    acc1[0] = acc1[1] = acc1[2] = acc1[3] = z2;
    acc2[0] = acc2[1] = acc2[2] = acc2[3] = z2;
    acc3[0] = acc3[1] = acc3[2] = acc3[3] = z2;
    if (e8 == 0) pkacc(acc0, self);
    if (e8 == 1) pkacc(acc1, self);
    if (e8 == 2) pkacc(acc2, self);
    if (e8 == 3) pkacc(acc3, self);
    // group B gathers: nodes 2,3 blocks 0..3 (issue before consuming group A)
    uint4 gB[8];
#pragma unroll
    for (int b = 0; b < 4; b++) {
        int u = __shfl(idx2, b * 8 + e8, 64);
        gB[b] = Z;
        if (u >= 0) gB[b] = hsv[(size_t)u * 8 + f8];
        int v = __shfl(idx3, b * 8 + e8, 64);
        gB[4 + b] = Z;
        if (v >= 0) gB[4 + b] = hsv[(size_t)v * 8 + f8];
    }
#pragma unroll
    for (int b = 0; b < 4; b++) { pkacc(acc0, gA[b]); pkacc(acc1, gA[4 + b]); }
#pragma unroll
    for (int b = 0; b < 4; b++) { pkacc(acc2, gB[b]); pkacc(acc3, gB[4 + b]); }
    // rare: deg in (32,64] -> blocks 4..7 from the idx vectors
    int tb0 = (d0 + 7) >> 3, tb1 = (d1 + 7) >> 3;
    int tb2 = (d2 + 7) >> 3, tb3 = (d3 + 7) >> 3;
    for (int b = 4; b < tb0 && b < 8; b++) {
        int u = __shfl(idx0, b * 8 + e8, 64);
        if (u >= 0) pkacc(acc0, hsv[(size_t)u * 8 + f8]);
    }
    for (int b = 4; b < tb1 && b < 8; b++) {
        int u = __shfl(idx1, b * 8 + e8, 64);
        if (u >= 0) pkacc(acc1, hsv[(size_t)u * 8 + f8]);
    }
    for (int b = 4; b < tb2 && b < 8; b++) {
        int u = __shfl(idx2, b * 8 + e8, 64);
        if (u >= 0) pkacc(acc2, hsv[(size_t)u * 8 + f8]);
    }
    for (int b = 4; b < tb3 && b < 8; b++) {
        int u = __shfl(idx3, b * 8 + e8, 64);
        if (u >= 0) pkacc(acc3, hsv[(size_t)u * 8 + f8]);
    }
    // ~never: deg > 64 (direct loads)
    for (int b = 8; b < tb0; b++) {
        int j = r0 + b * 8 + e8;
        if (j < r1) pkacc(acc0, hsv[(size_t)csr_src[j] * 8 + f8]);
    }
    for (int b = 8; b < tb1; b++) {
        int j = r1 + b * 8 + e8;
        if (j < r2) pkacc(acc1, hsv[(size_t)csr_src[j] * 8 + f8]);
    }
    for (int b = 8; b < tb2; b++) {
        int j = r2 + b * 8 + e8;
        if (j < r3) pkacc(acc2, hsv[(size_t)csr_src[j] * 8 + f8]);
    }
    for (int b = 8; b < tb3; b++) {
        int j = r3 + b * 8 + e8;
        if (j < r4) pkacc(acc3, hsv[(size_t)csr_src[j] * 8 + f8]);
    }
    // packed fp16 cross-lane reduce over the 8 edge slots, all 4 nodes
#pragma unroll
    for (int c = 0; c < 4; c++) {
        __half2 t0 = acc0[c];
        t0 = __hadd2(t0, shxor_h2(t0, 8));
        t0 = __hadd2(t0, shxor_h2(t0, 16));
        t0 = __hadd2(t0, shxor_h2(t0, 32));
        acc0[c] = t0;
        __half2 t1 = acc1[c];
        t1 = __hadd2(t1, shxor_h2(t1, 8));
        t1 = __hadd2(t1, shxor_h2(t1, 16));
        t1 = __hadd2(t1, shxor_h2(t1, 32));
        acc1[c] = t1;
        __half2 t2 = acc2[c];
        t2 = __hadd2(t2, shxor_h2(t2, 8));
        t2 = __hadd2(t2, shxor_h2(t2, 16));
        t2 = __hadd2(t2, shxor_h2(t2, 32));
        acc2[c] = t2;
        __half2 t3 = acc3[c];
        t3 = __hadd2(t3, shxor_h2(t3, 8));
        t3 = __hadd2(t3, shxor_h2(t3, 16));
        t3 = __hadd2(t3, shxor_h2(t3, 32));
        acc3[c] = t3;
    }
    if (e8 < 4) {
        int node = n0 + e8;
        const __half2* acc = (e8 == 0) ? acc0 : (e8 == 1) ? acc1 : (e8 == 2) ? acc2 : acc3;
        float dn = dinv[node];
        const float4* b4 = (const float4*)bias;
        float4 blo = b4[f8 * 2], bhi = b4[f8 * 2 + 1];
        float2 f0 = __half22float2(acc[0]);
        float2 f1 = __half22float2(acc[1]);
        float2 f2 = __half22float2(acc[2]);
        float2 f3 = __half22float2(acc[3]);
        float r[8];
        r[0] = fmaf(f0.x, dn, blo.x); r[1] = fmaf(f0.y, dn, blo.y);
        r[2] = fmaf(f1.x, dn, blo.z); r[3] = fmaf(f1.y, dn, blo.w);
        r[4] = fmaf(f2.x, dn, bhi.x); r[5] = fmaf(f2.y, dn, bhi.y);
        r[6] = fmaf(f3.x, dn, bhi.z); r[7] = fmaf(f3.y, dn, bhi.w);
#pragma unroll
        for (int c = 0; c < 8; c++) r[c] = r[c] > 0.f ? r[c] : 0.f;
        HU o;
        o.h[0] = __floats2half2_rn(r[0], r[1]);
        o.h[1] = __floats2half2_rn(r[2], r[3]);
        o.h[2] = __floats2half2_rn(r[4], r[5]);
        o.h[3] = __floats2half2_rn(r[6], r[7]);
        ((uint4*)out)[(size_t)node * 8 + f8] = o.u;
    }
}

// ------- normlin: GraphNorm(64) single-pass stats + linear 64x64 + dinv -----------
__global__ __launch_bounds__(512) void normlin_k(const __half* __restrict__ A,
    const int* __restrict__ gstart, const float* __restrict__ gw,
    const float* __restrict__ gb, const float* __restrict__ ga,
    const float* __restrict__ W, const float* __restrict__ dinv,
    __half* __restrict__ out) {
    __shared__ float sW[64 * 64];
    __shared__ float red[512], red2[512];
    __shared__ float sam[64], ssc[64];
    __shared__ float srow[8 * 64];
    int tid = threadIdx.x, lane = tid & 63, wid = tid >> 6;
    int g = blockIdx.x;
    int s = gstart[g], e = gstart[g + 1], cnt = e - s;
    float cntf = (float)(cnt > 1 ? cnt : 1);
    for (int i = tid; i < 64 * 64; i += 512) sW[i] = W[i];
    float sum = 0.f, sq = 0.f;
    for (int i = s + wid; i < e; i += 8) {
        float v = __half2float(A[(size_t)i * 64 + lane]);
        sum += v;
        sq = fmaf(v, v, sq);
    }
    red[tid] = sum; red2[tid] = sq;
    __syncthreads();
    for (int st = 4; st > 0; st >>= 1) {
        if (wid < st) { red[tid] += red[tid + st * 64]; red2[tid] += red2[tid + st * 64]; }
        __syncthreads();
    }
    if (tid < 64) {
        float m = red[tid] / cntf, q = red2[tid] / cntf;
        float am = ga[tid] * m;
        float var = q - 2.f * am * m + am * am;
        sam[tid] = am;
        ssc[tid] = gw[tid] * rsqrtf(var + GN_EPS);
    }
    __syncthreads();
    float am = sam[lane], sc = ssc[lane], bb = gb[lane];
    for (int i = s + wid; i < e; i += 8) {
        float nv = (__half2float(A[(size_t)i * 64 + lane]) - am) * sc + bb;
        srow[wid * 64 + lane] = nv;
        float acc = 0.f;
#pragma unroll
        for (int k = 0; k < 64; k++) acc = fmaf(srow[wid * 64 + k], sW[k * 64 + lane], acc);
        out[(size_t)i * 64 + lane] = __float2half(acc * dinv[i]);
    }
}

// ---------------- layer0: GraphNorm(16) + linear 16->64 (block per graph) ---------
__device__ __forceinline__ void l0_body(float* rows, int cnt, int s,
    const float* __restrict__ x, const float* __restrict__ gw,
    const float* __restrict__ gb, const float* __restrict__ ga,
    const float* sW, const float* __restrict__ dinv, __half* __restrict__ hs_out,
    float* red, float* red2, float* sstat, float* sscale, int tid) {
    int f = tid & 15, r = tid >> 4;
    int lane = tid & 63, wid = tid >> 6;
    float cntf = (float)(cnt > 1 ? cnt : 1);
    float sum = 0.f, sq = 0.f;
    for (int i = r; i < cnt; i += 32) {
        float v = x[(size_t)(s + i) * 16 + f];
        rows[i * 16 + f] = v;
        sum += v;
        sq = fmaf(v, v, sq);
    }
    red[tid] = sum; red2[tid] = sq;
    __syncthreads();
    for (int st = 16; st > 0; st >>= 1) {
        if (r < st) { red[tid] += red[tid + st * 16]; red2[tid] += red2[tid + st * 16]; }
        __syncthreads();
    }
    if (tid < 16) {
        float m = red[tid] / cntf, q = red2[tid] / cntf;
        float am = ga[tid] * m;
        sstat[tid] = am;
        sscale[tid] = gw[tid] * rsqrtf(q - 2.f * am * m + am * am + GN_EPS);
    }
    __syncthreads();
    float am = sstat[f], sc = sscale[f], bb = gb[f];
    for (int i = r; i < cnt; i += 32) rows[i * 16 + f] = (rows[i * 16 + f] - am) * sc + bb;
    __syncthreads();
    for (int i = wid; i < cnt; i += 8) {
        float acc = 0.f;
#pragma unroll
        for (int k = 0; k < 16; k++) acc = fmaf(rows[i * 16 + k], sW[k * 64 + lane], acc);
        hs_out[(size_t)(s + i) * 64 + lane] = __float2half(acc * dinv[s + i]);
    }
}

__global__ __launch_bounds__(512) void layer0_k(const float* __restrict__ x,
    const int* __restrict__ gstart, const float* __restrict__ gw,
    const float* __restrict__ gb, const float* __restrict__ ga,
    const float* __restrict__ W, const float* __restrict__ dinv,
    __half* __restrict__ hs_out, float* __restrict__ spill16) {
    __shared__ float sRows[CAP * 16];
    __shared__ float sW[16 * 64];
    __shared__ float red[512], red2[512];
    __shared__ float sstat[16], sscale[16];
    int tid = threadIdx.x;
    int g = blockIdx.x;
    int s = gstart[g], e = gstart[g + 1], cnt = e - s;
    for (int i = tid; i < 16 * 64; i += 512) sW[i] = W[i];
    __syncthreads();
    if (cnt <= CAP)
        l0_body(sRows, cnt, s, x, gw, gb, ga, sW, dinv, hs_out, red, red2, sstat, sscale, tid);
    else
        l0_body(spill16 + (size_t)s * 16, cnt, s, x, gw, gb, ga, sW, dinv, hs_out, red, red2, sstat, sscale, tid);
}

// ---------------- Pool + MLP head + softmax: block per graph ----------------
__global__ void pool_head_k(const __half* __restrict__ x, const int* __restrict__ gstart,
                            const float* __restrict__ Wd, const float* __restrict__ bd,
                            const float* __restrict__ Wo, const float* __restrict__ bo,
                            float* __restrict__ out) {
    __shared__ float red[256];
    __shared__ float sp[64];
    __shared__ float sh[64];
    __shared__ float sl[2];
    int g = blockIdx.x;
    int s = gstart[g], e = gstart[g + 1];
    int cnt = e - s;
    float cntf = (float)(cnt > 1 ? cnt : 1);
    int tid = threadIdx.x;
    int f = tid & 63, r = tid >> 6;
    float sum = 0.f;
    for (int i = s + r; i < e; i += 4) sum += __half2float(x[(size_t)i * 64 + f]);
    red[tid] = sum;
    __syncthreads();
    for (int st = 2; st > 0; st >>= 1) {
        if (r < st) red[tid] += red[tid + st * 64];
        __syncthreads();
    }
    if (tid < 64) sp[tid] = red[tid] / cntf;
    __syncthreads();
    if (tid < 64) {
        float acc = bd[tid];
        for (int k = 0; k < 64; k++) acc = fmaf(sp[k], Wd[k * 64 + tid], acc);
        sh[tid] = acc > 0.f ? acc : 0.f;
    }
    __syncthreads();
    if (tid < 2) {
        float l = bo[tid];
        for (int k = 0; k < 64; k++) l = fmaf(sh[k], Wo[k * 2 + tid], l);
        sl[tid] = l;
    }
    __syncthreads();
    if (tid < 2) {
        float m = fmaxf(sl[0], sl[1]);
        float e0 = expf(sl[0] - m), e1 = expf(sl[1] - m);
        out[g * 2 + tid] = (tid == 0 ? e0 : e1) / (e0 + e1);
    }
}

extern "C" void kernel_launch(void* const* d_in, const int* in_sizes, int n_in,
                              void* d_out, int out_size, void* d_ws, size_t ws_size,
                              hipStream_t stream) {
    const float* x    = (const float*)d_in[0];
    const int* ei     = (const int*)d_in[1];
    const int* batch  = (const int*)d_in[2];
    const float* gn0w = (const float*)d_in[3];
    const float* gn0b = (const float*)d_in[4];
    const float* gn0a = (const float*)d_in[5];
    const float* W1   = (const float*)d_in[6];
    const float* b1   = (const float*)d_in[7];
    const float* gn1w = (const float*)d_in[8];
    const float* gn1b = (const float*)d_in[9];
    const float* gn1a = (const float*)d_in[10];
    const float* W2   = (const float*)d_in[11];
    const float* b2   = (const float*)d_in[12];
    const float* gn2w = (const float*)d_in[13];
    const float* gn2b = (const float*)d_in[14];
    const float* gn2a = (const float*)d_in[15];
    const float* W3   = (const float*)d_in[16];
    const float* b3   = (const float*)d_in[17];
    const float* Wd   = (const float*)d_in[18];
    const float* bd   = (const float*)d_in[19];
    const float* Wo   = (const float*)d_in[20];
    const float* bo   = (const float*)d_in[21];

    char* p = (char*)d_ws;
    auto alloc = [&](size_t bytes) -> void* {
        void* r = (void*)p;
        p += (bytes + 255) & ~(size_t)255;
        return r;
    };
    __half* A        = (__half*)alloc((size_t)NB_NODES * 64 * 2);
    __half* B        = (__half*)alloc((size_t)NB_NODES * 64 * 2);
    int* rowptr      = (int*)alloc((size_t)(NB_NODES + 1) * 4);
    unsigned* ebuf   = (unsigned*)alloc((size_t)NB_EDGES * 4);
    int* csr_src     = (int*)alloc((size_t)NB_EDGES * 4);
    int* hist        = (int*)alloc((size_t)NBLK1 * NBUCK * 4);
    int* total       = (int*)alloc((size_t)NBUCK * 4);
    float* dinv      = (float*)alloc((size_t)NB_NODES * 4);
    int* gstart      = (int*)alloc((size_t)(NB_GRAPHS + 1) * 4);
    float* spill16   = (float*)alloc((size_t)NB_NODES * 16 * 4);

    k1_hist<<<NBLK1, 256, 0, stream>>>(ei + NB_EDGES, hist, batch, gstart);
    k2a_scan<<<NBUCK, 512, 0, stream>>>(hist, total);
    k3_scatter<<<NBLK1, 256, 0, stream>>>(ei, hist, total, ebuf);
    k4_fine<<<NBUCK, 256, 0, stream>>>(ebuf, total, csr_src, rowptr, dinv);

    layer0_k<<<NB_GRAPHS, 512, 0, stream>>>(x, gstart, gn0w, gn0b, gn0a, W1, dinv, B, spill16);
    aggregate_h_k<<<6250, 256, 0, stream>>>(B, rowptr, csr_src, dinv, b1, A);
    normlin_k<<<NB_GRAPHS, 512, 0, stream>>>(A, gstart, gn1w, gn1b, gn1a, W2, dinv, B);
    aggregate_h_k<<<6250, 256, 0, stream>>>(B, rowptr, csr_src, dinv, b2, A);
    normlin_k<<<NB_GRAPHS, 512, 0, stream>>>(A, gstart, gn2w, gn2b, gn2a, W3, dinv, B);
    aggregate_h_k<<<6250, 256, 0, stream>>>(B, rowptr, csr_src, dinv, b3, A);
    pool_head_k<<<NB_GRAPHS, 256, 0, stream>>>(A, gstart, Wd, bd, Wo, bo, (float*)d_out);
}